// Round 6
// baseline (10540.327 us; speedup 1.0000x reference)
//
#include <hip/hip_runtime.h>
#include <hip/hip_fp16.h>

// ReviewAnalyzeModel: 2-layer biLSTM, B=64 T=512 E=256 H=256, V=50000.
// prep(cvt fp16) -> GEMM proj0 -> scan0 -> GEMM proj1 -> scan1 -> final linear.
// Scan R6: 16 blocks x 512 thr (8 waves). group gid=blockIdx&7 = (dir, batch-slice
// of 16); blk=blockIdx>>3 owns 128 of 256 hidden cols. Whh fragment in VGPRs/AGPRs.
// Own-half h exchanged via LDS (barrier); peer half via global ring (= h0 buffer,
// slot t+1, guard slots 0/513). Sync: 2 participants/group — tid0 release-store
// flag after barrier; all threads relaxed-poll peer flag + ONE acquire. Peer loads
// issued before own-half MFMA so LDS compute hides the cross-XCD load latency.

typedef _Float16 f16;
typedef _Float16 half8 __attribute__((ext_vector_type(8)));
typedef float floatx4 __attribute__((ext_vector_type(4)));

#if __has_builtin(__builtin_amdgcn_global_load_lds)
#define HAS_GLL 1
#endif

#if __has_builtin(__builtin_amdgcn_exp2f)
#define EXP2F __builtin_amdgcn_exp2f
#else
#define EXP2F exp2f
#endif
#if __has_builtin(__builtin_amdgcn_rcpf)
#define RCPF __builtin_amdgcn_rcpf
#else
#define RCPF(x) (1.0f/(x))
#endif

__device__ __forceinline__ float sigf(float x) {
  return RCPF(1.f + EXP2F(-1.4426950408889634f * x));
}
__device__ __forceinline__ float tanhf_(float x) {
  return 2.f * RCPF(1.f + EXP2F(-2.8853900817779268f * x)) - 1.f;
}

// ---------------- prep kernels ----------------

__global__ void k_cvt_embed(const float* __restrict__ src, f16* __restrict__ dst, int n8) {
  int i = blockIdx.x * blockDim.x + threadIdx.x;
  if (i >= n8) return;
  const float4* s = (const float4*)(src + (size_t)i * 8);
  float4 a = s[0], b = s[1];
  half8 h = { (f16)a.x,(f16)a.y,(f16)a.z,(f16)a.w,(f16)b.x,(f16)b.y,(f16)b.z,(f16)b.w };
  *(half8*)(dst + (size_t)i * 8) = h;
}

// dst[n'][k], n' = d*1024 + j*4 + gate ; src row (gate*256+j) of Wih_l?_{f,b}
__global__ void k_cvt_wih(const float* __restrict__ sf, const float* __restrict__ sb,
                          f16* __restrict__ dst, int K, int logK, int total) {
  int i = blockIdx.x * blockDim.x + threadIdx.x;
  if (i >= total) return;
  int k = i & (K - 1);
  int n = i >> logK;
  int d = n >> 10;
  int rem = n & 1023;
  int j = rem >> 2, g = rem & 3;
  const float* s = d ? sb : sf;
  dst[i] = (f16)s[(size_t)((g << 8) + j) * K + k];
}

__global__ void k_cvt_whh(const float* __restrict__ sf, const float* __restrict__ sb,
                          f16* __restrict__ dst) {
  int i = blockIdx.x * blockDim.x + threadIdx.x;
  if (i >= 524288) return;
  int d = i >> 18, rem = i & 262143;
  dst[i] = (f16)((d ? sb : sf)[rem]);
}

// ---------------- GEMM: C[m][n] = sum_k A[m][k]*B[n][k], C fp16 [M][2048] ----------------

template<int KD, bool GATHER>
__global__ __launch_bounds__(256)
void k_gemm(const f16* __restrict__ Abase, const f16* __restrict__ Bmat,
            const int* __restrict__ xtok, f16* __restrict__ C) {
  __shared__ __align__(16) char Al[128 * 64 * 2];
  __shared__ __align__(16) char Bl[128 * 64 * 2];
  __shared__ int toks[128];
  const int tid = threadIdx.x;
  const int lane = tid & 63, wave = tid >> 6;
  const int mt = blockIdx.x & 255;
  const int nt = blockIdx.x >> 8;
  const int Mb = mt * 128, Nb = nt * 128;

  if (GATHER) {
    if (tid < 128) {
      int m = Mb + tid;
      toks[tid] = xtok[(m & 63) * 512 + (m >> 6)];
    }
  }
  __syncthreads();

  const f16* asrc[4]; const f16* bsrc[4];
#pragma unroll
  for (int it = 0; it < 4; ++it) {
    int g = it * 256 + tid;
    int row = g >> 3, gc = g & 7;
    if (GATHER) asrc[it] = Abase + (size_t)toks[row] * KD + gc * 8;
    else        asrc[it] = Abase + (size_t)(Mb + row) * KD + gc * 8;
    bsrc[it] = Bmat + (size_t)(Nb + row) * KD + gc * 8;
  }

  floatx4 acc[4][4];
#pragma unroll
  for (int mi = 0; mi < 4; ++mi)
#pragma unroll
    for (int ni = 0; ni < 4; ++ni)
      acc[mi][ni] = (floatx4){0.f, 0.f, 0.f, 0.f};

  const int wr = wave >> 1, wc = wave & 1;

  for (int kt = 0; kt < KD / 64; ++kt) {
    __syncthreads();
#ifdef HAS_GLL
#pragma unroll
    for (int it = 0; it < 4; ++it) {
      __builtin_amdgcn_global_load_lds(
          (const __attribute__((address_space(1))) void*)(asrc[it]),
          (__attribute__((address_space(3))) void*)(Al + (it * 256 + wave * 64) * 16), 16, 0, 0);
      __builtin_amdgcn_global_load_lds(
          (const __attribute__((address_space(1))) void*)(bsrc[it]),
          (__attribute__((address_space(3))) void*)(Bl + (it * 256 + wave * 64) * 16), 16, 0, 0);
      asrc[it] += 64; bsrc[it] += 64;
    }
#else
    uint4 va[4], vb[4];
#pragma unroll
    for (int it = 0; it < 4; ++it) {
      va[it] = *(const uint4*)(asrc[it]);
      vb[it] = *(const uint4*)(bsrc[it]);
      asrc[it] += 64; bsrc[it] += 64;
    }
#pragma unroll
    for (int it = 0; it < 4; ++it) {
      *(uint4*)(Al + (it * 256 + wave * 64) * 16 + lane * 16) = va[it];
      *(uint4*)(Bl + (it * 256 + wave * 64) * 16 + lane * 16) = vb[it];
    }
#endif
    __syncthreads();

#pragma unroll
    for (int kk = 0; kk < 2; ++kk) {
      half8 av[4], bv[4];
#pragma unroll
      for (int mi = 0; mi < 4; ++mi) {
        int row = wr * 64 + mi * 16 + (lane & 15);
        av[mi] = *(const half8*)(Al + row * 128 + kk * 64 + (lane >> 4) * 16);
      }
#pragma unroll
      for (int ni = 0; ni < 4; ++ni) {
        int row = wc * 64 + ni * 16 + (lane & 15);
        bv[ni] = *(const half8*)(Bl + row * 128 + kk * 64 + (lane >> 4) * 16);
      }
#pragma unroll
      for (int mi = 0; mi < 4; ++mi)
#pragma unroll
        for (int ni = 0; ni < 4; ++ni)
          acc[mi][ni] = __builtin_amdgcn_mfma_f32_16x16x32_f16(av[mi], bv[ni], acc[mi][ni], 0, 0, 0);
    }
  }

#pragma unroll
  for (int mi = 0; mi < 4; ++mi) {
#pragma unroll
    for (int ni = 0; ni < 4; ++ni) {
      floatx4 v = acc[mi][ni];
      int n = Nb + wc * 64 + ni * 16 + (lane & 15);
#pragma unroll
      for (int r = 0; r < 4; ++r) {
        int m = Mb + wr * 64 + mi * 16 + (lane >> 4) * 4 + r;
        C[(size_t)m * 2048 + n] = (f16)v[r];
      }
    }
  }
}

// ---------------- scan kernel (R6: 2 blocks/group, LDS own-half, ring=h0) ----------------

template<int LAYER>
__global__ __launch_bounds__(512, 2)
void k_scan(const f16* __restrict__ proj, const f16* __restrict__ whh,
            const float* __restrict__ bias_f, const float* __restrict__ bias_b,
            f16* ring, float* __restrict__ finalh, unsigned* __restrict__ ctr) {
  __shared__ __align__(16) char Hl[8192];  // 2 x [16 rows][128 cols] fp16, XOR-swizzled
  const int tid = threadIdx.x, lane = tid & 63, wave = tid >> 6;
  const int gid = blockIdx.x & 7, blk = blockIdx.x >> 3;
  const int d = gid & 1, bgrp = gid >> 1;
  const int bbase = bgrp * 16;
  const int ownbase = blk * 128, peerbase = 128 - ownbase;
  const int rowsel = lane >> 4, l15 = lane & 15;
  const int jlocal = ownbase + wave * 16 + l15;   // output col within d-half (0..255)
  const int klocal = wave * 16 + l15;             // col within own 128-slice
  const int bA = l15;                              // A-fragment batch row
  unsigned* flagOwn  = ctr + gid * 64 + blk * 16;        // own flag (64B-separated)
  unsigned* flagPeer = ctr + gid * 64 + (1 - blk) * 16;  // peer flag

  // Whh fragment: wreg[g][kk] = B-fragment (gate g, absolute k-chunk kk)
  half8 wreg[4][8];
#pragma unroll
  for (int g = 0; g < 4; ++g)
#pragma unroll
    for (int kk = 0; kk < 8; ++kk)
      wreg[g][kk] = *(const half8*)(whh + ((size_t)(d * 1024 + g * 256 + jlocal)) * 256
                                    + kk * 32 + rowsel * 8);

  const float* bptr = d ? bias_b : bias_f;
  float bias[4];
#pragma unroll
  for (int g = 0; g < 4; ++g) bias[g] = bptr[g * 256 + jlocal];

  // prologue zeros: LDS (both parity buffers) + own chunk of the ring guard slot
  *(uint4*)(Hl + tid * 16) = make_uint4(0, 0, 0, 0);
  {
    const int gslot = d ? 513 : 0;
    int zr = tid >> 5, zc = (tid & 31) * 4;
    *(uint2*)(ring + ((size_t)gslot * 64 + bbase + zr) * 512 + d * 256 + ownbase + zc) =
        make_uint2(0, 0);
  }
  __syncthreads();
  if (tid == 0)
    __hip_atomic_store(flagOwn, 1u, __ATOMIC_RELEASE, __HIP_MEMORY_SCOPE_AGENT);

  float cst[4] = {0.f, 0.f, 0.f, 0.f};

  // prologue: proj row for step 0
  uint2 pj[4];
  {
    int t0 = d ? 511 : 0;
#pragma unroll
    for (int r = 0; r < 4; ++r)
      pj[r] = *(const uint2*)(proj + ((size_t)t0 * 64 + bbase + rowsel * 4 + r) * 2048
                              + d * 1024 + (size_t)jlocal * 4);
  }

  for (int s = 0; s < 512; ++s) {
    // 1) wait for peer's slot publish (flag >= s+1): relaxed poll + ONE acquire
    {
      unsigned target = (unsigned)(s + 1);
      unsigned v; int gd = 0;
      do {
        v = __hip_atomic_load(flagPeer, __ATOMIC_RELAXED, __HIP_MEMORY_SCOPE_AGENT);
      } while (v < target && ++gd < (1 << 18));
      (void)__hip_atomic_load(flagPeer, __ATOMIC_ACQUIRE, __HIP_MEMORY_SCOPE_AGENT);
    }

    // 2) issue peer-half loads (cross-XCD latency hidden under own-half MFMA)
    const int rslot = d ? 513 - s : s;
    uint4 a4p[4];
    {
      const f16* pr = ring + ((size_t)rslot * 64 + bbase + bA) * 512 + d * 256 + peerbase
                      + rowsel * 8;
#pragma unroll
      for (int i = 0; i < 4; ++i)
        a4p[i] = *(const uint4*)(pr + i * 32);
    }
    // prefetch next step's proj alongside
    uint2 pjn[4];
    {
      int sn = (s < 511) ? s + 1 : 511;
      int tn = d ? 511 - sn : sn;
#pragma unroll
      for (int r = 0; r < 4; ++r)
        pjn[r] = *(const uint2*)(proj + ((size_t)tn * 64 + bbase + rowsel * 4 + r) * 2048
                                 + d * 1024 + (size_t)jlocal * 4);
    }

    // 3) acc = proj + bias
    floatx4 acc[4];
#pragma unroll
    for (int r = 0; r < 4; ++r) {
      union { uint2 u; f16 h[4]; } cv; cv.u = pj[r];
      acc[0][r] = (float)cv.h[0] + bias[0];
      acc[1][r] = (float)cv.h[1] + bias[1];
      acc[2][r] = (float)cv.h[2] + bias[2];
      acc[3][r] = (float)cv.h[3] + bias[3];
    }

    // 4) own-half MFMA from LDS (parity (s&1)^1), swizzled
    {
      const int rb = ((s & 1) ^ 1) * 4096;
      const int swz = (bA & 7) << 4;
#pragma unroll
      for (int i = 0; i < 4; ++i) {
        uint4 a4o = *(const uint4*)(Hl + rb + ((bA * 256 + i * 64 + rowsel * 16) ^ swz));
        half8 av = __builtin_bit_cast(half8, a4o);
#pragma unroll
        for (int g = 0; g < 4; ++g)
          acc[g] = __builtin_amdgcn_mfma_f32_16x16x32_f16(av, wreg[g][(ownbase >> 5) + i],
                                                          acc[g], 0, 0, 0);
      }
    }

    // 5) peer-half MFMA (waits on a4p)
#pragma unroll
    for (int i = 0; i < 4; ++i) {
      half8 av = __builtin_bit_cast(half8, a4p[i]);
#pragma unroll
      for (int g = 0; g < 4; ++g)
        acc[g] = __builtin_amdgcn_mfma_f32_16x16x32_f16(av, wreg[g][(peerbase >> 5) + i],
                                                        acc[g], 0, 0, 0);
    }

    // 6) gates -> h, c
    const int tin = d ? 511 - s : s;
    const int wslot = d ? 512 - s : s + 1;
    float hvv[4];
    f16 hhv[4];
#pragma unroll
    for (int r = 0; r < 4; ++r) {
      float iv = sigf(acc[0][r]);
      float fv = sigf(acc[1][r]);
      float gv = tanhf_(acc[2][r]);
      float ov = sigf(acc[3][r]);
      cst[r] = fv * cst[r] + iv * gv;
      hvv[r] = ov * tanhf_(cst[r]);
      hhv[r] = (f16)hvv[r];
    }

    // 7) stores: LDS own-half (parity s&1, swizzled) + ring own chunk
    {
      char* wbuf = Hl + (s & 1) * 4096;
#pragma unroll
      for (int r = 0; r < 4; ++r) {
        int row = rowsel * 4 + r;
        *(f16*)(wbuf + ((row * 256 + klocal * 2) ^ ((row & 7) << 4))) = hhv[r];
        ring[((size_t)wslot * 64 + bbase + row) * 512 + d * 256 + jlocal] = hhv[r];
      }
    }
    if (LAYER == 1 && s == 511) {
#pragma unroll
      for (int r = 0; r < 4; ++r)
        finalh[(size_t)(d * 64 + bbase + rowsel * 4 + r) * 256 + jlocal] = hvv[r];
    }

    // 8) barrier (drains all waves' stores; LDS parity handoff), then publish
    __syncthreads();
    if (tid == 0)
      __hip_atomic_store(flagOwn, (unsigned)(s + 2), __ATOMIC_RELEASE,
                         __HIP_MEMORY_SCOPE_AGENT);

#pragma unroll
    for (int r = 0; r < 4; ++r) pj[r] = pjn[r];
  }
}

// ---------------- final linear ----------------
__global__ void k_final(const float* __restrict__ fh, const float* __restrict__ wlin,
                        const float* __restrict__ blin, float* __restrict__ out) {
  int tid = threadIdx.x;
  int b = tid >> 2, part = tid & 3;
  float sum = 0.f;
#pragma unroll 4
  for (int jj = 0; jj < 128; ++jj) {
    int j = part * 128 + jj;
    float lastv = (j < 256) ? fh[b * 256 + j] : fh[(64 + b) * 256 + (j - 256)];
    sum += lastv * wlin[j];
  }
  sum += __shfl_xor(sum, 1);
  sum += __shfl_xor(sum, 2);
  if (part == 0) out[b] = sum + blin[0];
}

// ---------------- host ----------------
extern "C" void kernel_launch(void* const* d_in, const int* in_sizes, int n_in,
                              void* d_out, int out_size, void* d_ws, size_t ws_size,
                              hipStream_t stream) {
  const int*   x     = (const int*)  d_in[0];
  const float* embed = (const float*)d_in[1];
  const float* wih0f = (const float*)d_in[2];
  const float* whh0f = (const float*)d_in[3];
  const float* b0f   = (const float*)d_in[4];
  const float* wih0b = (const float*)d_in[5];
  const float* whh0b = (const float*)d_in[6];
  const float* b0b   = (const float*)d_in[7];
  const float* wih1f = (const float*)d_in[8];
  const float* whh1f = (const float*)d_in[9];
  const float* b1f   = (const float*)d_in[10];
  const float* wih1b = (const float*)d_in[11];
  const float* whh1b = (const float*)d_in[12];
  const float* b1b   = (const float*)d_in[13];
  const float* wlin  = (const float*)d_in[14];
  const float* blin  = (const float*)d_in[15];

  char* ws = (char*)d_ws;
  size_t off = 0;
  auto alloc = [&](size_t bytes) {
    char* p = ws + off;
    off = (off + bytes + 511) & ~(size_t)511;
    return p;
  };
  f16* embed16 = (f16*)alloc((size_t)50000 * 256 * 2);
  f16* wih0_16 = (f16*)alloc((size_t)2048 * 256 * 2);
  f16* wih1_16 = (f16*)alloc((size_t)2048 * 512 * 2);
  f16* whh0_16 = (f16*)alloc((size_t)2 * 1024 * 256 * 2);
  f16* whh1_16 = (f16*)alloc((size_t)2 * 1024 * 256 * 2);
  f16* proj    = (f16*)alloc((size_t)32768 * 2048 * 2);
  f16* ring    = (f16*)alloc((size_t)514 * 64 * 512 * 2);  // exchange ring; slots 1..512 = h0
  float* fh    = (float*)alloc((size_t)2 * 64 * 256 * 4);
  unsigned* ctr = (unsigned*)alloc((size_t)8 * 64 * 4);

  if (off > ws_size) {
    hipMemsetAsync(d_out, 0, (size_t)out_size * 4, stream);
    return;
  }

  k_cvt_embed<<<(12800000 / 8 + 255) / 256, 256, 0, stream>>>(embed, embed16, 12800000 / 8);
  k_cvt_wih<<<(2048 * 256 + 255) / 256, 256, 0, stream>>>(wih0f, wih0b, wih0_16, 256, 8, 2048 * 256);
  k_cvt_wih<<<(2048 * 512 + 255) / 256, 256, 0, stream>>>(wih1f, wih1b, wih1_16, 512, 9, 2048 * 512);
  k_cvt_whh<<<(524288 + 255) / 256, 256, 0, stream>>>(whh0f, whh0b, whh0_16);
  k_cvt_whh<<<(524288 + 255) / 256, 256, 0, stream>>>(whh1f, whh1b, whh1_16);

  // layer 0 input projection: [32768,256] x [2048,256]^T -> proj
  k_gemm<256, true><<<4096, 256, 0, stream>>>(embed16, wih0_16, x, proj);
  hipMemsetAsync(ctr, 0, (size_t)8 * 64 * 4, stream);
  k_scan<0><<<16, 512, 0, stream>>>(proj, whh0_16, b0f, b0b, ring, nullptr, ctr);

  // layer 1 input projection: A = ring slots 1..512 ([32768,512]), B = wih1
  k_gemm<512, false><<<4096, 256, 0, stream>>>(ring + 32768, wih1_16, nullptr, proj);
  hipMemsetAsync(ctr, 0, (size_t)8 * 64 * 4, stream);
  k_scan<1><<<16, 512, 0, stream>>>(proj, whh1_16, b1f, b1b, ring, fh, ctr);

  k_final<<<1, 256, 0, stream>>>(fh, wlin, blin, (float*)d_out);
}

// Round 7
// 3877.265 us; speedup vs baseline: 2.7185x; 2.7185x over previous
//
#include <hip/hip_runtime.h>
#include <hip/hip_fp16.h>

// ReviewAnalyzeModel: 2-layer biLSTM, B=64 T=512 E=256 H=256, V=50000.
// prep(cvt fp16) -> GEMM proj0 -> scan0 -> GEMM proj1 -> scan1 -> final linear.
// Scan R7 (= R6 structure + compile-time OWNBASE to keep weights in VGPRs):
// 16 blocks x 512 thr (8 waves). group gid=blockIdx&7 = (dir, batch-slice of 16);
// blk owns 128 of 256 hidden cols (OWNBASE template param -> all reg indices static).
// Own-half h via LDS (one barrier); peer half via global ring (= h0 buffer, slot
// t+1, guard slots 0/513). Sync: tid0 release-store flag after barrier; all threads
// relaxed-poll peer flag + per-wave single acquire. Peer loads issued before
// own-half MFMA so LDS compute hides cross-XCD latency.

typedef _Float16 f16;
typedef _Float16 half8 __attribute__((ext_vector_type(8)));
typedef float floatx4 __attribute__((ext_vector_type(4)));

#if __has_builtin(__builtin_amdgcn_global_load_lds)
#define HAS_GLL 1
#endif

#if __has_builtin(__builtin_amdgcn_exp2f)
#define EXP2F __builtin_amdgcn_exp2f
#else
#define EXP2F exp2f
#endif
#if __has_builtin(__builtin_amdgcn_rcpf)
#define RCPF __builtin_amdgcn_rcpf
#else
#define RCPF(x) (1.0f/(x))
#endif

__device__ __forceinline__ float sigf(float x) {
  return RCPF(1.f + EXP2F(-1.4426950408889634f * x));
}
__device__ __forceinline__ float tanhf_(float x) {
  return 2.f * RCPF(1.f + EXP2F(-2.8853900817779268f * x)) - 1.f;
}

// ---------------- prep kernels ----------------

__global__ void k_cvt_embed(const float* __restrict__ src, f16* __restrict__ dst, int n8) {
  int i = blockIdx.x * blockDim.x + threadIdx.x;
  if (i >= n8) return;
  const float4* s = (const float4*)(src + (size_t)i * 8);
  float4 a = s[0], b = s[1];
  half8 h = { (f16)a.x,(f16)a.y,(f16)a.z,(f16)a.w,(f16)b.x,(f16)b.y,(f16)b.z,(f16)b.w };
  *(half8*)(dst + (size_t)i * 8) = h;
}

// dst[n'][k], n' = d*1024 + j*4 + gate ; src row (gate*256+j) of Wih_l?_{f,b}
__global__ void k_cvt_wih(const float* __restrict__ sf, const float* __restrict__ sb,
                          f16* __restrict__ dst, int K, int logK, int total) {
  int i = blockIdx.x * blockDim.x + threadIdx.x;
  if (i >= total) return;
  int k = i & (K - 1);
  int n = i >> logK;
  int d = n >> 10;
  int rem = n & 1023;
  int j = rem >> 2, g = rem & 3;
  const float* s = d ? sb : sf;
  dst[i] = (f16)s[(size_t)((g << 8) + j) * K + k];
}

__global__ void k_cvt_whh(const float* __restrict__ sf, const float* __restrict__ sb,
                          f16* __restrict__ dst) {
  int i = blockIdx.x * blockDim.x + threadIdx.x;
  if (i >= 524288) return;
  int d = i >> 18, rem = i & 262143;
  dst[i] = (f16)((d ? sb : sf)[rem]);
}

// ---------------- GEMM: C[m][n] = sum_k A[m][k]*B[n][k], C fp16 [M][2048] ----------------

template<int KD, bool GATHER>
__global__ __launch_bounds__(256)
void k_gemm(const f16* __restrict__ Abase, const f16* __restrict__ Bmat,
            const int* __restrict__ xtok, f16* __restrict__ C) {
  __shared__ __align__(16) char Al[128 * 64 * 2];
  __shared__ __align__(16) char Bl[128 * 64 * 2];
  __shared__ int toks[128];
  const int tid = threadIdx.x;
  const int lane = tid & 63, wave = tid >> 6;
  const int mt = blockIdx.x & 255;
  const int nt = blockIdx.x >> 8;
  const int Mb = mt * 128, Nb = nt * 128;

  if (GATHER) {
    if (tid < 128) {
      int m = Mb + tid;
      toks[tid] = xtok[(m & 63) * 512 + (m >> 6)];
    }
  }
  __syncthreads();

  const f16* asrc[4]; const f16* bsrc[4];
#pragma unroll
  for (int it = 0; it < 4; ++it) {
    int g = it * 256 + tid;
    int row = g >> 3, gc = g & 7;
    if (GATHER) asrc[it] = Abase + (size_t)toks[row] * KD + gc * 8;
    else        asrc[it] = Abase + (size_t)(Mb + row) * KD + gc * 8;
    bsrc[it] = Bmat + (size_t)(Nb + row) * KD + gc * 8;
  }

  floatx4 acc[4][4];
#pragma unroll
  for (int mi = 0; mi < 4; ++mi)
#pragma unroll
    for (int ni = 0; ni < 4; ++ni)
      acc[mi][ni] = (floatx4){0.f, 0.f, 0.f, 0.f};

  const int wr = wave >> 1, wc = wave & 1;

  for (int kt = 0; kt < KD / 64; ++kt) {
    __syncthreads();
#ifdef HAS_GLL
#pragma unroll
    for (int it = 0; it < 4; ++it) {
      __builtin_amdgcn_global_load_lds(
          (const __attribute__((address_space(1))) void*)(asrc[it]),
          (__attribute__((address_space(3))) void*)(Al + (it * 256 + wave * 64) * 16), 16, 0, 0);
      __builtin_amdgcn_global_load_lds(
          (const __attribute__((address_space(1))) void*)(bsrc[it]),
          (__attribute__((address_space(3))) void*)(Bl + (it * 256 + wave * 64) * 16), 16, 0, 0);
      asrc[it] += 64; bsrc[it] += 64;
    }
#else
    uint4 va[4], vb[4];
#pragma unroll
    for (int it = 0; it < 4; ++it) {
      va[it] = *(const uint4*)(asrc[it]);
      vb[it] = *(const uint4*)(bsrc[it]);
      asrc[it] += 64; bsrc[it] += 64;
    }
#pragma unroll
    for (int it = 0; it < 4; ++it) {
      *(uint4*)(Al + (it * 256 + wave * 64) * 16 + lane * 16) = va[it];
      *(uint4*)(Bl + (it * 256 + wave * 64) * 16 + lane * 16) = vb[it];
    }
#endif
    __syncthreads();

#pragma unroll
    for (int kk = 0; kk < 2; ++kk) {
      half8 av[4], bv[4];
#pragma unroll
      for (int mi = 0; mi < 4; ++mi) {
        int row = wr * 64 + mi * 16 + (lane & 15);
        av[mi] = *(const half8*)(Al + row * 128 + kk * 64 + (lane >> 4) * 16);
      }
#pragma unroll
      for (int ni = 0; ni < 4; ++ni) {
        int row = wc * 64 + ni * 16 + (lane & 15);
        bv[ni] = *(const half8*)(Bl + row * 128 + kk * 64 + (lane >> 4) * 16);
      }
#pragma unroll
      for (int mi = 0; mi < 4; ++mi)
#pragma unroll
        for (int ni = 0; ni < 4; ++ni)
          acc[mi][ni] = __builtin_amdgcn_mfma_f32_16x16x32_f16(av[mi], bv[ni], acc[mi][ni], 0, 0, 0);
    }
  }

#pragma unroll
  for (int mi = 0; mi < 4; ++mi) {
#pragma unroll
    for (int ni = 0; ni < 4; ++ni) {
      floatx4 v = acc[mi][ni];
      int n = Nb + wc * 64 + ni * 16 + (lane & 15);
#pragma unroll
      for (int r = 0; r < 4; ++r) {
        int m = Mb + wr * 64 + mi * 16 + (lane >> 4) * 4 + r;
        C[(size_t)m * 2048 + n] = (f16)v[r];
      }
    }
  }
}

// ---------------- scan body (OWNBASE is COMPILE-TIME: keeps wreg[] in VGPRs) ----------------

template<int LAYER, int OWNBASE>
__device__ __forceinline__ void scan_body(
    const f16* __restrict__ proj, const f16* __restrict__ whh,
    const float* __restrict__ bias_f, const float* __restrict__ bias_b,
    f16* ring, float* __restrict__ finalh, unsigned* __restrict__ ctr,
    char* Hl) {
  constexpr int PEERBASE = 128 - OWNBASE;
  constexpr int BLK = OWNBASE >> 7;
  const int tid = threadIdx.x, lane = tid & 63, wave = tid >> 6;
  const int gid = blockIdx.x & 7;
  const int d = gid & 1, bgrp = gid >> 1;
  const int bbase = bgrp * 16;
  const int rowsel = lane >> 4, l15 = lane & 15;
  const int jlocal = OWNBASE + wave * 16 + l15;   // output col within d-half (0..255)
  const int klocal = wave * 16 + l15;             // col within own 128-slice
  const int bA = l15;                              // A-fragment batch row
  unsigned* flagOwn  = ctr + gid * 64 + BLK * 16;
  unsigned* flagPeer = ctr + gid * 64 + (1 - BLK) * 16;

  // Whh fragment: wreg[g][kk] = B-fragment (gate g, absolute k-chunk kk) — static idx only
  half8 wreg[4][8];
#pragma unroll
  for (int g = 0; g < 4; ++g)
#pragma unroll
    for (int kk = 0; kk < 8; ++kk)
      wreg[g][kk] = *(const half8*)(whh + ((size_t)(d * 1024 + g * 256 + jlocal)) * 256
                                    + kk * 32 + rowsel * 8);

  const float* bptr = d ? bias_b : bias_f;
  float bias[4];
#pragma unroll
  for (int g = 0; g < 4; ++g) bias[g] = bptr[g * 256 + jlocal];

  // prologue zeros: LDS (both parity buffers) + own chunk of the ring guard slot
  *(uint4*)(Hl + tid * 16) = make_uint4(0, 0, 0, 0);
  {
    const int gslot = d ? 513 : 0;
    int zr = tid >> 5, zc = (tid & 31) * 4;
    *(uint2*)(ring + ((size_t)gslot * 64 + bbase + zr) * 512 + d * 256 + OWNBASE + zc) =
        make_uint2(0, 0);
  }
  __syncthreads();
  if (tid == 0)
    __hip_atomic_store(flagOwn, 1u, __ATOMIC_RELEASE, __HIP_MEMORY_SCOPE_AGENT);

  float cst[4] = {0.f, 0.f, 0.f, 0.f};

  // prologue: proj row for step 0
  uint2 pj[4];
  {
    int t0 = d ? 511 : 0;
#pragma unroll
    for (int r = 0; r < 4; ++r)
      pj[r] = *(const uint2*)(proj + ((size_t)t0 * 64 + bbase + rowsel * 4 + r) * 2048
                              + d * 1024 + (size_t)jlocal * 4);
  }

  for (int s = 0; s < 512; ++s) {
    // 1) wait for peer's slot publish (flag >= s+1): relaxed poll + ONE acquire
    {
      unsigned target = (unsigned)(s + 1);
      unsigned v; int gd = 0;
      do {
        v = __hip_atomic_load(flagPeer, __ATOMIC_RELAXED, __HIP_MEMORY_SCOPE_AGENT);
      } while (v < target && ++gd < (1 << 18));
      (void)__hip_atomic_load(flagPeer, __ATOMIC_ACQUIRE, __HIP_MEMORY_SCOPE_AGENT);
    }

    // 2) issue peer-half loads (cross-XCD latency hidden under own-half MFMA)
    const int rslot = d ? 513 - s : s;
    uint4 a4p[4];
    {
      const f16* pr = ring + ((size_t)rslot * 64 + bbase + bA) * 512 + d * 256 + PEERBASE
                      + rowsel * 8;
#pragma unroll
      for (int i = 0; i < 4; ++i)
        a4p[i] = *(const uint4*)(pr + i * 32);
    }
    // prefetch next step's proj alongside
    uint2 pjn[4];
    {
      int sn = (s < 511) ? s + 1 : 511;
      int tn = d ? 511 - sn : sn;
#pragma unroll
      for (int r = 0; r < 4; ++r)
        pjn[r] = *(const uint2*)(proj + ((size_t)tn * 64 + bbase + rowsel * 4 + r) * 2048
                                 + d * 1024 + (size_t)jlocal * 4);
    }

    // 3) acc = proj + bias
    floatx4 acc[4];
#pragma unroll
    for (int r = 0; r < 4; ++r) {
      union { uint2 u; f16 h[4]; } cv; cv.u = pj[r];
      acc[0][r] = (float)cv.h[0] + bias[0];
      acc[1][r] = (float)cv.h[1] + bias[1];
      acc[2][r] = (float)cv.h[2] + bias[2];
      acc[3][r] = (float)cv.h[3] + bias[3];
    }

    // 4) own-half MFMA from LDS (parity (s&1)^1), swizzled; static wreg idx
    {
      const int rb = ((s & 1) ^ 1) * 4096;
      const int swz = (bA & 7) << 4;
#pragma unroll
      for (int i = 0; i < 4; ++i) {
        uint4 a4o = *(const uint4*)(Hl + rb + ((bA * 256 + i * 64 + rowsel * 16) ^ swz));
        half8 av = __builtin_bit_cast(half8, a4o);
#pragma unroll
        for (int g = 0; g < 4; ++g)
          acc[g] = __builtin_amdgcn_mfma_f32_16x16x32_f16(av, wreg[g][(OWNBASE >> 5) + i],
                                                          acc[g], 0, 0, 0);
      }
    }

    // 5) peer-half MFMA (waits on a4p); static wreg idx
#pragma unroll
    for (int i = 0; i < 4; ++i) {
      half8 av = __builtin_bit_cast(half8, a4p[i]);
#pragma unroll
      for (int g = 0; g < 4; ++g)
        acc[g] = __builtin_amdgcn_mfma_f32_16x16x32_f16(av, wreg[g][(PEERBASE >> 5) + i],
                                                        acc[g], 0, 0, 0);
    }

    // 6) gates -> h, c
    const int wslot = d ? 512 - s : s + 1;
    float hvv[4];
    f16 hhv[4];
#pragma unroll
    for (int r = 0; r < 4; ++r) {
      float iv = sigf(acc[0][r]);
      float fv = sigf(acc[1][r]);
      float gv = tanhf_(acc[2][r]);
      float ov = sigf(acc[3][r]);
      cst[r] = fv * cst[r] + iv * gv;
      hvv[r] = ov * tanhf_(cst[r]);
      hhv[r] = (f16)hvv[r];
    }

    // 7) stores: LDS own-half (parity s&1, swizzled) + ring own chunk
    {
      char* wbuf = Hl + (s & 1) * 4096;
#pragma unroll
      for (int r = 0; r < 4; ++r) {
        int row = rowsel * 4 + r;
        *(f16*)(wbuf + ((row * 256 + klocal * 2) ^ ((row & 7) << 4))) = hhv[r];
        ring[((size_t)wslot * 64 + bbase + row) * 512 + d * 256 + jlocal] = hhv[r];
      }
    }
    if (LAYER == 1 && s == 511) {
#pragma unroll
      for (int r = 0; r < 4; ++r)
        finalh[(size_t)(d * 64 + bbase + rowsel * 4 + r) * 256 + jlocal] = hvv[r];
    }

    // 8) barrier (drains all waves' stores; LDS parity handoff), then publish
    __syncthreads();
    if (tid == 0)
      __hip_atomic_store(flagOwn, (unsigned)(s + 2), __ATOMIC_RELEASE,
                         __HIP_MEMORY_SCOPE_AGENT);

#pragma unroll
    for (int r = 0; r < 4; ++r) pj[r] = pjn[r];
  }
}

template<int LAYER>
__global__ __launch_bounds__(512, 2)
void k_scan(const f16* __restrict__ proj, const f16* __restrict__ whh,
            const float* __restrict__ bias_f, const float* __restrict__ bias_b,
            f16* ring, float* __restrict__ finalh, unsigned* __restrict__ ctr) {
  __shared__ __align__(16) char Hl[8192];  // 2 x [16 rows][128 cols] fp16, XOR-swizzled
  if ((blockIdx.x >> 3) == 0)
    scan_body<LAYER, 0>(proj, whh, bias_f, bias_b, ring, finalh, ctr, Hl);
  else
    scan_body<LAYER, 128>(proj, whh, bias_f, bias_b, ring, finalh, ctr, Hl);
}

// ---------------- final linear ----------------
__global__ void k_final(const float* __restrict__ fh, const float* __restrict__ wlin,
                        const float* __restrict__ blin, float* __restrict__ out) {
  int tid = threadIdx.x;
  int b = tid >> 2, part = tid & 3;
  float sum = 0.f;
#pragma unroll 4
  for (int jj = 0; jj < 128; ++jj) {
    int j = part * 128 + jj;
    float lastv = (j < 256) ? fh[b * 256 + j] : fh[(64 + b) * 256 + (j - 256)];
    sum += lastv * wlin[j];
  }
  sum += __shfl_xor(sum, 1);
  sum += __shfl_xor(sum, 2);
  if (part == 0) out[b] = sum + blin[0];
}

// ---------------- host ----------------
extern "C" void kernel_launch(void* const* d_in, const int* in_sizes, int n_in,
                              void* d_out, int out_size, void* d_ws, size_t ws_size,
                              hipStream_t stream) {
  const int*   x     = (const int*)  d_in[0];
  const float* embed = (const float*)d_in[1];
  const float* wih0f = (const float*)d_in[2];
  const float* whh0f = (const float*)d_in[3];
  const float* b0f   = (const float*)d_in[4];
  const float* wih0b = (const float*)d_in[5];
  const float* whh0b = (const float*)d_in[6];
  const float* b0b   = (const float*)d_in[7];
  const float* wih1f = (const float*)d_in[8];
  const float* whh1f = (const float*)d_in[9];
  const float* b1f   = (const float*)d_in[10];
  const float* wih1b = (const float*)d_in[11];
  const float* whh1b = (const float*)d_in[12];
  const float* b1b   = (const float*)d_in[13];
  const float* wlin  = (const float*)d_in[14];
  const float* blin  = (const float*)d_in[15];

  char* ws = (char*)d_ws;
  size_t off = 0;
  auto alloc = [&](size_t bytes) {
    char* p = ws + off;
    off = (off + bytes + 511) & ~(size_t)511;
    return p;
  };
  f16* embed16 = (f16*)alloc((size_t)50000 * 256 * 2);
  f16* wih0_16 = (f16*)alloc((size_t)2048 * 256 * 2);
  f16* wih1_16 = (f16*)alloc((size_t)2048 * 512 * 2);
  f16* whh0_16 = (f16*)alloc((size_t)2 * 1024 * 256 * 2);
  f16* whh1_16 = (f16*)alloc((size_t)2 * 1024 * 256 * 2);
  f16* proj    = (f16*)alloc((size_t)32768 * 2048 * 2);
  f16* ring    = (f16*)alloc((size_t)514 * 64 * 512 * 2);  // exchange ring; slots 1..512 = h0
  float* fh    = (float*)alloc((size_t)2 * 64 * 256 * 4);
  unsigned* ctr = (unsigned*)alloc((size_t)8 * 64 * 4);

  if (off > ws_size) {
    hipMemsetAsync(d_out, 0, (size_t)out_size * 4, stream);
    return;
  }

  k_cvt_embed<<<(12800000 / 8 + 255) / 256, 256, 0, stream>>>(embed, embed16, 12800000 / 8);
  k_cvt_wih<<<(2048 * 256 + 255) / 256, 256, 0, stream>>>(wih0f, wih0b, wih0_16, 256, 8, 2048 * 256);
  k_cvt_wih<<<(2048 * 512 + 255) / 256, 256, 0, stream>>>(wih1f, wih1b, wih1_16, 512, 9, 2048 * 512);
  k_cvt_whh<<<(524288 + 255) / 256, 256, 0, stream>>>(whh0f, whh0b, whh0_16);
  k_cvt_whh<<<(524288 + 255) / 256, 256, 0, stream>>>(whh1f, whh1b, whh1_16);

  // layer 0 input projection: [32768,256] x [2048,256]^T -> proj
  k_gemm<256, true><<<4096, 256, 0, stream>>>(embed16, wih0_16, x, proj);
  hipMemsetAsync(ctr, 0, (size_t)8 * 64 * 4, stream);
  k_scan<0><<<16, 512, 0, stream>>>(proj, whh0_16, b0f, b0b, ring, nullptr, ctr);

  // layer 1 input projection: A = ring slots 1..512 ([32768,512]), B = wih1
  k_gemm<512, false><<<4096, 256, 0, stream>>>(ring + 32768, wih1_16, nullptr, proj);
  hipMemsetAsync(ctr, 0, (size_t)8 * 64 * 4, stream);
  k_scan<1><<<16, 512, 0, stream>>>(proj, whh1_16, b1f, b1b, ring, fh, ctr);

  k_final<<<1, 256, 0, stream>>>(fh, wlin, blin, (float*)d_out);
}

// Round 9
// 3154.035 us; speedup vs baseline: 3.3419x; 1.2293x over previous
//
#include <hip/hip_runtime.h>
#include <hip/hip_fp16.h>

// ReviewAnalyzeModel: 2-layer biLSTM, B=64 T=512 E=256 H=256, V=50000.
// prep(cvt fp16) -> GEMM proj0 -> scan0 -> GEMM proj1 -> scan1 -> final linear.
// Scan R9 (= R7 structure + tid0-only poll/acquire, barrier-broadcast):
// 16 blocks x 512 thr (8 waves). group gid=blockIdx&7 = (dir, batch-slice of 16);
// blk owns 128 of 256 hidden cols (compile-time OWNBASE -> weights stay in regs).
// Own-half h via LDS; peer half via global ring (= h0 buffer, slot t+1, guard
// slots 0/513). Sync per step, ALL compiler atomics:
//   consume: tid0 relaxed-poll peer flag + ONE acquire, __syncthreads broadcast
//   publish: stores -> __syncthreads (vmcnt drain) -> tid0 release-store flag
// 2 release + 2 acquire per group-step total (R7 had 2+16 -> its 8.9k cy/step).

typedef _Float16 f16;
typedef _Float16 half8 __attribute__((ext_vector_type(8)));
typedef float floatx4 __attribute__((ext_vector_type(4)));

#if __has_builtin(__builtin_amdgcn_global_load_lds)
#define HAS_GLL 1
#endif

#if __has_builtin(__builtin_amdgcn_exp2f)
#define EXP2F __builtin_amdgcn_exp2f
#else
#define EXP2F exp2f
#endif
#if __has_builtin(__builtin_amdgcn_rcpf)
#define RCPF __builtin_amdgcn_rcpf
#else
#define RCPF(x) (1.0f/(x))
#endif

__device__ __forceinline__ float sigf(float x) {
  return RCPF(1.f + EXP2F(-1.4426950408889634f * x));
}
__device__ __forceinline__ float tanhf_(float x) {
  return 2.f * RCPF(1.f + EXP2F(-2.8853900817779268f * x)) - 1.f;
}

// ---------------- prep kernels ----------------

__global__ void k_cvt_embed(const float* __restrict__ src, f16* __restrict__ dst, int n8) {
  int i = blockIdx.x * blockDim.x + threadIdx.x;
  if (i >= n8) return;
  const float4* s = (const float4*)(src + (size_t)i * 8);
  float4 a = s[0], b = s[1];
  half8 h = { (f16)a.x,(f16)a.y,(f16)a.z,(f16)a.w,(f16)b.x,(f16)b.y,(f16)b.z,(f16)b.w };
  *(half8*)(dst + (size_t)i * 8) = h;
}

// dst[n'][k], n' = d*1024 + j*4 + gate ; src row (gate*256+j) of Wih_l?_{f,b}
__global__ void k_cvt_wih(const float* __restrict__ sf, const float* __restrict__ sb,
                          f16* __restrict__ dst, int K, int logK, int total) {
  int i = blockIdx.x * blockDim.x + threadIdx.x;
  if (i >= total) return;
  int k = i & (K - 1);
  int n = i >> logK;
  int d = n >> 10;
  int rem = n & 1023;
  int j = rem >> 2, g = rem & 3;
  const float* s = d ? sb : sf;
  dst[i] = (f16)s[(size_t)((g << 8) + j) * K + k];
}

__global__ void k_cvt_whh(const float* __restrict__ sf, const float* __restrict__ sb,
                          f16* __restrict__ dst) {
  int i = blockIdx.x * blockDim.x + threadIdx.x;
  if (i >= 524288) return;
  int d = i >> 18, rem = i & 262143;
  dst[i] = (f16)((d ? sb : sf)[rem]);
}

// ---------------- GEMM: C[m][n] = sum_k A[m][k]*B[n][k], C fp16 [M][2048] ----------------

template<int KD, bool GATHER>
__global__ __launch_bounds__(256)
void k_gemm(const f16* __restrict__ Abase, const f16* __restrict__ Bmat,
            const int* __restrict__ xtok, f16* __restrict__ C) {
  __shared__ __align__(16) char Al[128 * 64 * 2];
  __shared__ __align__(16) char Bl[128 * 64 * 2];
  __shared__ int toks[128];
  const int tid = threadIdx.x;
  const int lane = tid & 63, wave = tid >> 6;
  const int mt = blockIdx.x & 255;
  const int nt = blockIdx.x >> 8;
  const int Mb = mt * 128, Nb = nt * 128;

  if (GATHER) {
    if (tid < 128) {
      int m = Mb + tid;
      toks[tid] = xtok[(m & 63) * 512 + (m >> 6)];
    }
  }
  __syncthreads();

  const f16* asrc[4]; const f16* bsrc[4];
#pragma unroll
  for (int it = 0; it < 4; ++it) {
    int g = it * 256 + tid;
    int row = g >> 3, gc = g & 7;
    if (GATHER) asrc[it] = Abase + (size_t)toks[row] * KD + gc * 8;
    else        asrc[it] = Abase + (size_t)(Mb + row) * KD + gc * 8;
    bsrc[it] = Bmat + (size_t)(Nb + row) * KD + gc * 8;
  }

  floatx4 acc[4][4];
#pragma unroll
  for (int mi = 0; mi < 4; ++mi)
#pragma unroll
    for (int ni = 0; ni < 4; ++ni)
      acc[mi][ni] = (floatx4){0.f, 0.f, 0.f, 0.f};

  const int wr = wave >> 1, wc = wave & 1;

  for (int kt = 0; kt < KD / 64; ++kt) {
    __syncthreads();
#ifdef HAS_GLL
#pragma unroll
    for (int it = 0; it < 4; ++it) {
      __builtin_amdgcn_global_load_lds(
          (const __attribute__((address_space(1))) void*)(asrc[it]),
          (__attribute__((address_space(3))) void*)(Al + (it * 256 + wave * 64) * 16), 16, 0, 0);
      __builtin_amdgcn_global_load_lds(
          (const __attribute__((address_space(1))) void*)(bsrc[it]),
          (__attribute__((address_space(3))) void*)(Bl + (it * 256 + wave * 64) * 16), 16, 0, 0);
      asrc[it] += 64; bsrc[it] += 64;
    }
#else
    uint4 va[4], vb[4];
#pragma unroll
    for (int it = 0; it < 4; ++it) {
      va[it] = *(const uint4*)(asrc[it]);
      vb[it] = *(const uint4*)(bsrc[it]);
      asrc[it] += 64; bsrc[it] += 64;
    }
#pragma unroll
    for (int it = 0; it < 4; ++it) {
      *(uint4*)(Al + (it * 256 + wave * 64) * 16 + lane * 16) = va[it];
      *(uint4*)(Bl + (it * 256 + wave * 64) * 16 + lane * 16) = vb[it];
    }
#endif
    __syncthreads();

#pragma unroll
    for (int kk = 0; kk < 2; ++kk) {
      half8 av[4], bv[4];
#pragma unroll
      for (int mi = 0; mi < 4; ++mi) {
        int row = wr * 64 + mi * 16 + (lane & 15);
        av[mi] = *(const half8*)(Al + row * 128 + kk * 64 + (lane >> 4) * 16);
      }
#pragma unroll
      for (int ni = 0; ni < 4; ++ni) {
        int row = wc * 64 + ni * 16 + (lane & 15);
        bv[ni] = *(const half8*)(Bl + row * 128 + kk * 64 + (lane >> 4) * 16);
      }
#pragma unroll
      for (int mi = 0; mi < 4; ++mi)
#pragma unroll
        for (int ni = 0; ni < 4; ++ni)
          acc[mi][ni] = __builtin_amdgcn_mfma_f32_16x16x32_f16(av[mi], bv[ni], acc[mi][ni], 0, 0, 0);
    }
  }

#pragma unroll
  for (int mi = 0; mi < 4; ++mi) {
#pragma unroll
    for (int ni = 0; ni < 4; ++ni) {
      floatx4 v = acc[mi][ni];
      int n = Nb + wc * 64 + ni * 16 + (lane & 15);
#pragma unroll
      for (int r = 0; r < 4; ++r) {
        int m = Mb + wr * 64 + mi * 16 + (lane >> 4) * 4 + r;
        C[(size_t)m * 2048 + n] = (f16)v[r];
      }
    }
  }
}

// ---------------- scan body (OWNBASE is COMPILE-TIME: keeps wreg[] in VGPRs) ----------------

template<int LAYER, int OWNBASE>
__device__ __forceinline__ void scan_body(
    const f16* __restrict__ proj, const f16* __restrict__ whh,
    const float* __restrict__ bias_f, const float* __restrict__ bias_b,
    f16* ring, float* __restrict__ finalh, unsigned* __restrict__ ctr,
    char* Hl) {
  constexpr int PEERBASE = 128 - OWNBASE;
  constexpr int BLK = OWNBASE >> 7;
  const int tid = threadIdx.x, lane = tid & 63, wave = tid >> 6;
  const int gid = blockIdx.x & 7;
  const int d = gid & 1, bgrp = gid >> 1;
  const int bbase = bgrp * 16;
  const int rowsel = lane >> 4, l15 = lane & 15;
  const int jlocal = OWNBASE + wave * 16 + l15;   // output col within d-half (0..255)
  const int klocal = wave * 16 + l15;             // col within own 128-slice
  const int bA = l15;                              // A-fragment batch row
  unsigned* flagOwn  = ctr + gid * 64 + BLK * 16;
  unsigned* flagPeer = ctr + gid * 64 + (1 - BLK) * 16;

  // Whh fragment: wreg[g][kk] = B-fragment (gate g, absolute k-chunk kk) — static idx only
  half8 wreg[4][8];
#pragma unroll
  for (int g = 0; g < 4; ++g)
#pragma unroll
    for (int kk = 0; kk < 8; ++kk)
      wreg[g][kk] = *(const half8*)(whh + ((size_t)(d * 1024 + g * 256 + jlocal)) * 256
                                    + kk * 32 + rowsel * 8);

  const float* bptr = d ? bias_b : bias_f;
  float bias[4];
#pragma unroll
  for (int g = 0; g < 4; ++g) bias[g] = bptr[g * 256 + jlocal];

  // prologue zeros: LDS (both parity buffers) + own chunk of the ring guard slot
  *(uint4*)(Hl + tid * 16) = make_uint4(0, 0, 0, 0);
  {
    const int gslot = d ? 513 : 0;
    int zr = tid >> 5, zc = (tid & 31) * 4;
    *(uint2*)(ring + ((size_t)gslot * 64 + bbase + zr) * 512 + d * 256 + OWNBASE + zc) =
        make_uint2(0, 0);
  }
  __syncthreads();
  if (tid == 0)
    __hip_atomic_store(flagOwn, 1u, __ATOMIC_RELEASE, __HIP_MEMORY_SCOPE_AGENT);

  float cst[4] = {0.f, 0.f, 0.f, 0.f};

  // prologue: proj row for step 0
  uint2 pj[4];
  {
    int t0 = d ? 511 : 0;
#pragma unroll
    for (int r = 0; r < 4; ++r)
      pj[r] = *(const uint2*)(proj + ((size_t)t0 * 64 + bbase + rowsel * 4 + r) * 2048
                              + d * 1024 + (size_t)jlocal * 4);
  }

  for (int s = 0; s < 512; ++s) {
    // 1) consume: tid0-only relaxed poll of peer flag (>= s+1) + ONE acquire,
    //    then barrier-broadcast (L1 is per-CU => block-wide visibility).
    if (tid == 0) {
      unsigned target = (unsigned)(s + 1);
      unsigned v; int gd = 0;
      do {
        v = __hip_atomic_load(flagPeer, __ATOMIC_RELAXED, __HIP_MEMORY_SCOPE_AGENT);
      } while (v < target && ++gd < (1 << 18));
      (void)__hip_atomic_load(flagPeer, __ATOMIC_ACQUIRE, __HIP_MEMORY_SCOPE_AGENT);
    }
    __syncthreads();

    // 2) issue peer-half loads (latency hidden under own-half LDS MFMA)
    const int rslot = d ? 513 - s : s;
    uint4 a4p[4];
    {
      const f16* pr = ring + ((size_t)rslot * 64 + bbase + bA) * 512 + d * 256 + PEERBASE
                      + rowsel * 8;
#pragma unroll
      for (int i = 0; i < 4; ++i)
        a4p[i] = *(const uint4*)(pr + i * 32);
    }
    // prefetch next step's proj alongside
    uint2 pjn[4];
    {
      int sn = (s < 511) ? s + 1 : 511;
      int tn = d ? 511 - sn : sn;
#pragma unroll
      for (int r = 0; r < 4; ++r)
        pjn[r] = *(const uint2*)(proj + ((size_t)tn * 64 + bbase + rowsel * 4 + r) * 2048
                                 + d * 1024 + (size_t)jlocal * 4);
    }

    // 3) acc = proj + bias
    floatx4 acc[4];
#pragma unroll
    for (int r = 0; r < 4; ++r) {
      union { uint2 u; f16 h[4]; } cv; cv.u = pj[r];
      acc[0][r] = (float)cv.h[0] + bias[0];
      acc[1][r] = (float)cv.h[1] + bias[1];
      acc[2][r] = (float)cv.h[2] + bias[2];
      acc[3][r] = (float)cv.h[3] + bias[3];
    }

    // 4) own-half MFMA from LDS (parity (s&1)^1), swizzled; static wreg idx
    {
      const int rb = ((s & 1) ^ 1) * 4096;
      const int swz = (bA & 7) << 4;
#pragma unroll
      for (int i = 0; i < 4; ++i) {
        uint4 a4o = *(const uint4*)(Hl + rb + ((bA * 256 + i * 64 + rowsel * 16) ^ swz));
        half8 av = __builtin_bit_cast(half8, a4o);
#pragma unroll
        for (int g = 0; g < 4; ++g)
          acc[g] = __builtin_amdgcn_mfma_f32_16x16x32_f16(av, wreg[g][(OWNBASE >> 5) + i],
                                                          acc[g], 0, 0, 0);
      }
    }

    // 5) peer-half MFMA (waits on a4p); static wreg idx
#pragma unroll
    for (int i = 0; i < 4; ++i) {
      half8 av = __builtin_bit_cast(half8, a4p[i]);
#pragma unroll
      for (int g = 0; g < 4; ++g)
        acc[g] = __builtin_amdgcn_mfma_f32_16x16x32_f16(av, wreg[g][(PEERBASE >> 5) + i],
                                                        acc[g], 0, 0, 0);
    }

    // 6) gates -> h, c
    const int wslot = d ? 512 - s : s + 1;
    float hvv[4];
    f16 hhv[4];
#pragma unroll
    for (int r = 0; r < 4; ++r) {
      float iv = sigf(acc[0][r]);
      float fv = sigf(acc[1][r]);
      float gv = tanhf_(acc[2][r]);
      float ov = sigf(acc[3][r]);
      cst[r] = fv * cst[r] + iv * gv;
      hvv[r] = ov * tanhf_(cst[r]);
      hhv[r] = (f16)hvv[r];
    }

    // 7) stores: LDS own-half (parity s&1, swizzled) + ring own chunk
    {
      char* wbuf = Hl + (s & 1) * 4096;
#pragma unroll
      for (int r = 0; r < 4; ++r) {
        int row = rowsel * 4 + r;
        *(f16*)(wbuf + ((row * 256 + klocal * 2) ^ ((row & 7) << 4))) = hhv[r];
        ring[((size_t)wslot * 64 + bbase + row) * 512 + d * 256 + jlocal] = hhv[r];
      }
    }
    if (LAYER == 1 && s == 511) {
#pragma unroll
      for (int r = 0; r < 4; ++r)
        finalh[(size_t)(d * 64 + bbase + rowsel * 4 + r) * 256 + jlocal] = hvv[r];
    }

    // 8) barrier (compiler drains vmcnt for all waves' stores), then tid0 publishes
    __syncthreads();
    if (tid == 0)
      __hip_atomic_store(flagOwn, (unsigned)(s + 2), __ATOMIC_RELEASE,
                         __HIP_MEMORY_SCOPE_AGENT);

#pragma unroll
    for (int r = 0; r < 4; ++r) pj[r] = pjn[r];
  }
}

template<int LAYER>
__global__ __launch_bounds__(512, 2)
void k_scan(const f16* __restrict__ proj, const f16* __restrict__ whh,
            const float* __restrict__ bias_f, const float* __restrict__ bias_b,
            f16* ring, float* __restrict__ finalh, unsigned* __restrict__ ctr) {
  __shared__ __align__(16) char Hl[8192];  // 2 x [16 rows][128 cols] fp16, XOR-swizzled
  if ((blockIdx.x >> 3) == 0)
    scan_body<LAYER, 0>(proj, whh, bias_f, bias_b, ring, finalh, ctr, Hl);
  else
    scan_body<LAYER, 128>(proj, whh, bias_f, bias_b, ring, finalh, ctr, Hl);
}

// ---------------- final linear ----------------
__global__ void k_final(const float* __restrict__ fh, const float* __restrict__ wlin,
                        const float* __restrict__ blin, float* __restrict__ out) {
  int tid = threadIdx.x;
  int b = tid >> 2, part = tid & 3;
  float sum = 0.f;
#pragma unroll 4
  for (int jj = 0; jj < 128; ++jj) {
    int j = part * 128 + jj;
    float lastv = (j < 256) ? fh[b * 256 + j] : fh[(64 + b) * 256 + (j - 256)];
    sum += lastv * wlin[j];
  }
  sum += __shfl_xor(sum, 1);
  sum += __shfl_xor(sum, 2);
  if (part == 0) out[b] = sum + blin[0];
}

// ---------------- host ----------------
extern "C" void kernel_launch(void* const* d_in, const int* in_sizes, int n_in,
                              void* d_out, int out_size, void* d_ws, size_t ws_size,
                              hipStream_t stream) {
  const int*   x     = (const int*)  d_in[0];
  const float* embed = (const float*)d_in[1];
  const float* wih0f = (const float*)d_in[2];
  const float* whh0f = (const float*)d_in[3];
  const float* b0f   = (const float*)d_in[4];
  const float* wih0b = (const float*)d_in[5];
  const float* whh0b = (const float*)d_in[6];
  const float* b0b   = (const float*)d_in[7];
  const float* wih1f = (const float*)d_in[8];
  const float* whh1f = (const float*)d_in[9];
  const float* b1f   = (const float*)d_in[10];
  const float* wih1b = (const float*)d_in[11];
  const float* whh1b = (const float*)d_in[12];
  const float* b1b   = (const float*)d_in[13];
  const float* wlin  = (const float*)d_in[14];
  const float* blin  = (const float*)d_in[15];

  char* ws = (char*)d_ws;
  size_t off = 0;
  auto alloc = [&](size_t bytes) {
    char* p = ws + off;
    off = (off + bytes + 511) & ~(size_t)511;
    return p;
  };
  f16* embed16 = (f16*)alloc((size_t)50000 * 256 * 2);
  f16* wih0_16 = (f16*)alloc((size_t)2048 * 256 * 2);
  f16* wih1_16 = (f16*)alloc((size_t)2048 * 512 * 2);
  f16* whh0_16 = (f16*)alloc((size_t)2 * 1024 * 256 * 2);
  f16* whh1_16 = (f16*)alloc((size_t)2 * 1024 * 256 * 2);
  f16* proj    = (f16*)alloc((size_t)32768 * 2048 * 2);
  f16* ring    = (f16*)alloc((size_t)514 * 64 * 512 * 2);  // exchange ring; slots 1..512 = h0
  float* fh    = (float*)alloc((size_t)2 * 64 * 256 * 4);
  unsigned* ctr = (unsigned*)alloc((size_t)8 * 64 * 4);

  if (off > ws_size) {
    hipMemsetAsync(d_out, 0, (size_t)out_size * 4, stream);
    return;
  }

  k_cvt_embed<<<(12800000 / 8 + 255) / 256, 256, 0, stream>>>(embed, embed16, 12800000 / 8);
  k_cvt_wih<<<(2048 * 256 + 255) / 256, 256, 0, stream>>>(wih0f, wih0b, wih0_16, 256, 8, 2048 * 256);
  k_cvt_wih<<<(2048 * 512 + 255) / 256, 256, 0, stream>>>(wih1f, wih1b, wih1_16, 512, 9, 2048 * 512);
  k_cvt_whh<<<(524288 + 255) / 256, 256, 0, stream>>>(whh0f, whh0b, whh0_16);
  k_cvt_whh<<<(524288 + 255) / 256, 256, 0, stream>>>(whh1f, whh1b, whh1_16);

  // layer 0 input projection: [32768,256] x [2048,256]^T -> proj
  k_gemm<256, true><<<4096, 256, 0, stream>>>(embed16, wih0_16, x, proj);
  hipMemsetAsync(ctr, 0, (size_t)8 * 64 * 4, stream);
  k_scan<0><<<16, 512, 0, stream>>>(proj, whh0_16, b0f, b0b, ring, nullptr, ctr);

  // layer 1 input projection: A = ring slots 1..512 ([32768,512]), B = wih1
  k_gemm<512, false><<<4096, 256, 0, stream>>>(ring + 32768, wih1_16, nullptr, proj);
  hipMemsetAsync(ctr, 0, (size_t)8 * 64 * 4, stream);
  k_scan<1><<<16, 512, 0, stream>>>(proj, whh1_16, b1f, b1b, ring, fh, ctr);

  k_final<<<1, 256, 0, stream>>>(fh, wlin, blin, (float*)d_out);
}